// Round 2
// baseline (156.299 us; speedup 1.0000x reference)
//
#include <hip/hip_runtime.h>
#include <hip/hip_fp16.h>
#include <stdint.h>

typedef _Float16 f16;
typedef _Float16 half8  __attribute__((ext_vector_type(8)));
typedef _Float16 half4v __attribute__((ext_vector_type(4)));
typedef float    f32x4  __attribute__((ext_vector_type(4)));

#define NBATCH 4
#define SEQ    4096
#define DMODEL 256
#define DHEAD  64
#define NQKV   192

// ---------------------------------------------------------------------------
// Kernel A: qkv = x @ W_qkv + b_qkv (fp32 VALU), emit fp16 q (pre-scaled by
// 1/8 = 1/sqrt(64), exact pow2 scale), k, v.  32 rows x 192 cols per WG.
// ---------------------------------------------------------------------------
__global__ __launch_bounds__(256) void qkv_proj(
    const float* __restrict__ x, const float* __restrict__ Wq,
    const float* __restrict__ bq,
    f16* __restrict__ qh, f16* __restrict__ kh, f16* __restrict__ vh)
{
  __shared__ float xs[32][64];      // 8 KB
  __shared__ float wsh[64][NQKV];   // 48 KB
  const int t = threadIdx.x;
  const int row0 = blockIdx.x * 32;
  const int cg = t & 31;            // 32 col-groups x 6 cols
  const int rg = t >> 5;            // 8 row-groups x 4 rows
  const int n0 = cg * 6;
  const int m0 = rg * 4;
  float acc[4][6];
#pragma unroll
  for (int i = 0; i < 4; ++i)
#pragma unroll
    for (int j = 0; j < 6; ++j) acc[i][j] = 0.f;

  for (int kc = 0; kc < 4; ++kc) {
    const int k0 = kc * 64;
#pragma unroll
    for (int j = 0; j < 8; ++j) {
      int li = j * 256 + t;
      xs[li >> 6][li & 63] = x[(size_t)(row0 + (li >> 6)) * DMODEL + k0 + (li & 63)];
    }
#pragma unroll
    for (int j = 0; j < 48; ++j) {
      int li = j * 256 + t;
      int r = li / NQKV, c = li % NQKV;
      wsh[r][c] = Wq[(size_t)(k0 + r) * NQKV + c];
    }
    __syncthreads();
#pragma unroll
    for (int kk4 = 0; kk4 < 16; ++kk4) {
      float4 a4[4];
#pragma unroll
      for (int i = 0; i < 4; ++i) a4[i] = *(const float4*)&xs[m0 + i][kk4 * 4];
#pragma unroll
      for (int e = 0; e < 4; ++e) {
        const int kk = kk4 * 4 + e;
        float2 b01 = *(const float2*)&wsh[kk][n0];
        float2 b23 = *(const float2*)&wsh[kk][n0 + 2];
        float2 b45 = *(const float2*)&wsh[kk][n0 + 4];
#pragma unroll
        for (int i = 0; i < 4; ++i) {
          const float a = (e == 0) ? a4[i].x : (e == 1) ? a4[i].y : (e == 2) ? a4[i].z : a4[i].w;
          acc[i][0] = fmaf(a, b01.x, acc[i][0]);
          acc[i][1] = fmaf(a, b01.y, acc[i][1]);
          acc[i][2] = fmaf(a, b23.x, acc[i][2]);
          acc[i][3] = fmaf(a, b23.y, acc[i][3]);
          acc[i][4] = fmaf(a, b45.x, acc[i][4]);
          acc[i][5] = fmaf(a, b45.y, acc[i][5]);
        }
      }
    }
    __syncthreads();
  }
#pragma unroll
  for (int i = 0; i < 4; ++i) {
    const size_t row = (size_t)row0 + m0 + i;
#pragma unroll
    for (int j = 0; j < 6; ++j) {
      const int n = n0 + j;
      const float v = acc[i][j] + bq[n];
      if (n < 64)        qh[row * DHEAD + n]         = (f16)(v * 0.125f);
      else if (n < 128)  kh[row * DHEAD + (n - 64)]  = (f16)v;
      else               vh[row * DHEAD + (n - 128)] = (f16)v;
    }
  }
}

// ---------------------------------------------------------------------------
// Kernel B: fused scores -> top-k threshold -> masked softmax -> PV.
// WG = 512 threads (8 waves) handles 16 q-rows; wave w owns keys [512w,512w+512).
// Swapped QK^T: mfma(A=K_tile, B=Q) gives S^T; lane (l&15)=q-row holds 128
// scores packed fp16 in registers. Threshold via sampled-count bisection.
// ---------------------------------------------------------------------------
#define WAVES  8
#define CHUNK  32
#define NCHUNK 16

__global__ __launch_bounds__(512) void attn_fused(
    const f16* __restrict__ qh, const f16* __restrict__ kh,
    const f16* __restrict__ vh, float* __restrict__ attn_out)
{
  __shared__ f16 stage[WAVES][CHUNK * DHEAD];  // 32 KB, wave-private staging / reduce
  __shared__ float selbuf[2][WAVES][16];
  __shared__ float zrow[16];

  const int tid = threadIdx.x;
  const int w = tid >> 6;
  const int l = tid & 63;
  const int qr = l & 15;          // q-row (QK^T) / n-col (PV) within tile
  const int g  = l >> 4;          // lane group 0..3
  const int bi = blockIdx.x >> 8;
  const int rb = blockIdx.x & 255;
  const size_t qrow0  = (size_t)bi * SEQ + (size_t)rb * 16;
  const size_t kvbase = (size_t)bi * SEQ * DHEAD;
  const int key0 = w * (CHUNK * NCHUNK);

  f16* const myst = &stage[w][0];

  // Q fragments (B operand), q pre-scaled by 1/8 in qh.
  half8 qf0, qf1;
  {
    const f16* qp = qh + (qrow0 + qr) * DHEAD;
    qf0 = *(const half8*)(qp + 8 * g);
    qf1 = *(const half8*)(qp + 32 + 8 * g);
  }

  half4v P[2 * NCHUNK];           // 128 fp16 scores/lane (row qr, keys of this wave)
  float mn = 1e30f, mx = -1e30f;

  // ---- QK^T: stage K chunk (swizzled), 2 MFMAs per 16-key tile ----
#pragma unroll
  for (int kc = 0; kc < NCHUNK; ++kc) {
    const f16* src = kh + kvbase + (size_t)(key0 + kc * CHUNK) * DHEAD;
#pragma unroll
    for (int i = 0; i < 4; ++i) {
      const int keyl = i * 8 + (l >> 3);
      const int c8 = l & 7;
      uint4 d = *(const uint4*)(src + keyl * DHEAD + c8 * 8);
      *(uint4*)(myst + keyl * DHEAD + ((c8 ^ (keyl & 7)) * 8)) = d;
    }
    // wave-private region: no barrier needed; DS ops are in-order per wave.
#pragma unroll
    for (int kt = 0; kt < 2; ++kt) {
      f32x4 c = {0.f, 0.f, 0.f, 0.f};
      const int keyl = kt * 16 + qr;   // A-row = key
      {
        const int ch0 = g;             // d-chunk 0: halves 8g..8g+7
        half8 kf0 = *(const half8*)(myst + keyl * DHEAD + ((ch0 ^ (keyl & 7)) * 8));
        c = __builtin_amdgcn_mfma_f32_16x16x32_f16(kf0, qf0, c, 0, 0, 0);
        const int ch1 = 4 + g;         // d-chunk 1: halves 32+8g..
        half8 kf1 = *(const half8*)(myst + keyl * DHEAD + ((ch1 ^ (keyl & 7)) * 8));
        c = __builtin_amdgcn_mfma_f32_16x16x32_f16(kf1, qf1, c, 0, 0, 0);
      }
      mn = fminf(mn, fminf(fminf(c[0], c[1]), fminf(c[2], c[3])));
      mx = fmaxf(mx, fmaxf(fmaxf(c[0], c[1]), fmaxf(c[2], c[3])));
      P[kc * 2 + kt] = (half4v){(f16)c[0], (f16)c[1], (f16)c[2], (f16)c[3]};
    }
  }

  // ---- per-row min/max across lanes and waves ----
  mn = fminf(mn, __shfl_xor(mn, 16, 64));
  mn = fminf(mn, __shfl_xor(mn, 32, 64));
  mx = fmaxf(mx, __shfl_xor(mx, 16, 64));
  mx = fmaxf(mx, __shfl_xor(mx, 32, 64));
  __syncthreads();
  if (l < 16) { selbuf[0][w][l] = mn; selbuf[1][w][l] = mx; }
  __syncthreads();
  float lo = 1e30f, hi = -1e30f;
#pragma unroll
  for (int j = 0; j < WAVES; ++j) {
    lo = fminf(lo, selbuf[0][j][qr]);
    hi = fmaxf(hi, selbuf[1][j][qr]);
  }

  // ---- bisection on sampled count (1024 of 4096 samples; target 512) ----
#pragma unroll
  for (int it = 0; it < 10; ++it) {
    const float tm = 0.5f * (lo + hi);
    const f16 th = (f16)tm;
    int cnt = 0;
#pragma unroll
    for (int j = 0; j < 2 * NCHUNK; j += 4) {
      half4v s = P[j];
      cnt += (s[0] >= th) + (s[1] >= th) + (s[2] >= th) + (s[3] >= th);
    }
    cnt += __shfl_xor(cnt, 16, 64);
    cnt += __shfl_xor(cnt, 32, 64);
    __syncthreads();
    if (l < 16) selbuf[it & 1][w][l] = (float)cnt;
    __syncthreads();
    float tot = 0.f;
#pragma unroll
    for (int j = 0; j < WAVES; ++j) tot += selbuf[it & 1][j][qr];
    if (tot >= 512.f) lo = tm; else hi = tm;
  }
  const float thr = lo;

  // ---- exp in place (masked -> exp(0)=1, matching softmax(scores*mask)) ----
  float z = 0.f;
#pragma unroll
  for (int j = 0; j < 2 * NCHUNK; ++j) {
    half4v s = P[j];
    float p0 = (float)s[0], p1 = (float)s[1], p2 = (float)s[2], p3 = (float)s[3];
    p0 = (p0 >= thr) ? __expf(p0) : 1.f;
    p1 = (p1 >= thr) ? __expf(p1) : 1.f;
    p2 = (p2 >= thr) ? __expf(p2) : 1.f;
    p3 = (p3 >= thr) ? __expf(p3) : 1.f;
    z += (p0 + p1) + (p2 + p3);
    P[j] = (half4v){(f16)p0, (f16)p1, (f16)p2, (f16)p3};
  }
  z += __shfl_xor(z, 16, 64);
  z += __shfl_xor(z, 32, 64);
  __syncthreads();
  if (l < 16) selbuf[0][w][l] = z;
  __syncthreads();
  if (w == 0 && l < 16) {
    float t2 = 0.f;
#pragma unroll
    for (int j = 0; j < WAVES; ++j) t2 += selbuf[0][j][l];
    zrow[l] = t2;   // read after the final barrier below
  }

  // ---- PV: A-frag = P (layout matches 16x16x16 A exactly), B-frag = V ----
  f32x4 acc[4];
#pragma unroll
  for (int p = 0; p < 4; ++p) acc[p] = (f32x4){0.f, 0.f, 0.f, 0.f};

#pragma unroll
  for (int kc = 0; kc < NCHUNK; ++kc) {
    const f16* src = vh + kvbase + (size_t)(key0 + kc * CHUNK) * DHEAD;
#pragma unroll
    for (int i = 0; i < 4; ++i) {
      const int keyl = i * 8 + (l >> 3);
      const int c8 = l & 7;
      uint4 d = *(const uint4*)(src + keyl * DHEAD + c8 * 8);
      *(uint4*)(myst + keyl * DHEAD + ((c8 ^ (keyl & 7)) * 8)) = d;
    }
#pragma unroll
    for (int kt = 0; kt < 2; ++kt) {
      const half4v pa = P[kc * 2 + kt];
#pragma unroll
      for (int pnl = 0; pnl < 4; ++pnl) {
        const int n = pnl * 16 + qr;
        const int nc = n >> 3, ni = n & 7;
        const int k0l = kt * 16 + 4 * g;
        f16 v0 = myst[(k0l + 0) * DHEAD + ((nc ^ ((k0l + 0) & 7)) << 3) + ni];
        f16 v1 = myst[(k0l + 1) * DHEAD + ((nc ^ ((k0l + 1) & 7)) << 3) + ni];
        f16 v2 = myst[(k0l + 2) * DHEAD + ((nc ^ ((k0l + 2) & 7)) << 3) + ni];
        f16 v3 = myst[(k0l + 3) * DHEAD + ((nc ^ ((k0l + 3) & 7)) << 3) + ni];
        half4v vv = {v0, v1, v2, v3};
        acc[pnl] = __builtin_amdgcn_mfma_f32_16x16x16f16(pa, vv, acc[pnl], 0, 0, 0);
      }
    }
  }

  // ---- cross-wave reduce + divide by Z ----
  float* red = (float*)myst;   // own 4 KB region = 16 rows x 64 cols fp32
#pragma unroll
  for (int pnl = 0; pnl < 4; ++pnl)
#pragma unroll
    for (int r = 0; r < 4; ++r)
      red[(4 * g + r) * DHEAD + pnl * 16 + qr] = acc[pnl][r];
  __syncthreads();
#pragma unroll
  for (int oo = 0; oo < 2; ++oo) {
    const int o = tid * 2 + oo;
    const int i = o >> 6, n = o & 63;
    float s = 0.f;
#pragma unroll
    for (int j = 0; j < WAVES; ++j) s += ((const float*)&stage[j][0])[i * DHEAD + n];
    attn_out[(qrow0 + i) * DHEAD + n] = s / zrow[i];
  }
}

// ---------------------------------------------------------------------------
// Kernel C: out = attn_out @ W_out + b_out (fp32). 32 rows x 256 cols per WG.
// ---------------------------------------------------------------------------
__global__ __launch_bounds__(256) void out_proj(
    const float* __restrict__ attn, const float* __restrict__ Wo,
    const float* __restrict__ bo, float* __restrict__ out)
{
  __shared__ float wl[32][DMODEL];  // 32 KB (K staged in 2 chunks)
  __shared__ float at[32][DHEAD];   // 8 KB
  const int t = threadIdx.x;
  const int row0 = blockIdx.x * 32;
  const int rg = t >> 6;            // 4 groups x 8 rows (one wave per group)
  const int cg = t & 63;            // 64 groups x 4 cols
  float acc[8][4];
#pragma unroll
  for (int i = 0; i < 8; ++i) { acc[i][0] = acc[i][1] = acc[i][2] = acc[i][3] = 0.f; }
#pragma unroll
  for (int j = 0; j < 8; ++j) {
    int li = j * 256 + t;
    at[li >> 6][li & 63] = attn[(size_t)(row0 + (li >> 6)) * DHEAD + (li & 63)];
  }
  for (int kc = 0; kc < 2; ++kc) {
#pragma unroll
    for (int j = 0; j < 32; ++j) {
      int li = j * 256 + t;
      wl[li >> 8][li & 255] = Wo[(size_t)(kc * 32 + (li >> 8)) * DMODEL + (li & 255)];
    }
    __syncthreads();
#pragma unroll
    for (int kk = 0; kk < 32; ++kk) {
      const float4 wv = *(const float4*)&wl[kk][cg * 4];
#pragma unroll
      for (int i = 0; i < 8; ++i) {
        const float a = at[rg * 8 + i][kc * 32 + kk];
        acc[i][0] = fmaf(a, wv.x, acc[i][0]);
        acc[i][1] = fmaf(a, wv.y, acc[i][1]);
        acc[i][2] = fmaf(a, wv.z, acc[i][2]);
        acc[i][3] = fmaf(a, wv.w, acc[i][3]);
      }
    }
    __syncthreads();
  }
  const float4 bb = *(const float4*)&bo[cg * 4];
#pragma unroll
  for (int i = 0; i < 8; ++i) {
    float4 r;
    r.x = acc[i][0] + bb.x; r.y = acc[i][1] + bb.y;
    r.z = acc[i][2] + bb.z; r.w = acc[i][3] + bb.w;
    *(float4*)&out[(size_t)(row0 + rg * 8 + i) * DMODEL + cg * 4] = r;
  }
}

// ---------------------------------------------------------------------------
extern "C" void kernel_launch(void* const* d_in, const int* in_sizes, int n_in,
                              void* d_out, int out_size, void* d_ws, size_t ws_size,
                              hipStream_t stream)
{
  (void)in_sizes; (void)n_in; (void)out_size; (void)ws_size;
  const float* x  = (const float*)d_in[0];
  const float* Wq = (const float*)d_in[1];
  const float* bq = (const float*)d_in[2];
  const float* Wo = (const float*)d_in[3];
  const float* bo = (const float*)d_in[4];
  float* out = (float*)d_out;
  char* ws = (char*)d_ws;
  f16* qh = (f16*)(ws);                              // 2 MB
  f16* kh = (f16*)(ws + (size_t)(2 << 20));          // 2 MB
  f16* vh = (f16*)(ws + (size_t)(4 << 20));          // 2 MB
  float* attn = (float*)(ws + (size_t)(6 << 20));    // 4 MB

  hipLaunchKernelGGL(qkv_proj,   dim3(512),  dim3(256), 0, stream, x, Wq, bq, qh, kh, vh);
  hipLaunchKernelGGL(attn_fused, dim3(1024), dim3(512), 0, stream, qh, kh, vh, attn);
  hipLaunchKernelGGL(out_proj,   dim3(512),  dim3(256), 0, stream, attn, Wo, bo, out);
}